// Round 3
// baseline (747.697 us; speedup 1.0000x reference)
//
#include <hip/hip_runtime.h>
#include <hip/hip_bf16.h>

#define N_TOK 4096
#define H_DIM 1024
#define V_DIM 50257
#define IGNORE_IDX (-100)

// fallback-path params
#define BM 128
#define BN 128
#define BK 64
#define NCHUNK_FB ((V_DIM + BN - 1) / BN)   /* 393 */
#define LDT 72

// pipelined-path params
#define KS 32                     /* K per step */
#define NT (H_DIM / KS)           /* 32 steps */
#define NB 4                      /* LDS ring slots */
#define DD 3                      /* pipeline depth = NB-1 */
#define SLOT_BYTES 32768          /* A 16K + B 16K */
#define NCH2 ((V_DIM + 255) / 256) /* 197 */

typedef __attribute__((ext_vector_type(8))) short bf16x8;
typedef __attribute__((ext_vector_type(4))) float f32x4;

union Pack8 { __hip_bfloat162 h2[4]; int4 v; };

__device__ __forceinline__ void gload16(const void* g, void* l) {
    __builtin_amdgcn_global_load_lds(
        (const __attribute__((address_space(1))) unsigned int*)g,
        (__attribute__((address_space(3))) unsigned int*)l,
        16, 0, 0);
}

#define FENCE() do { asm volatile("" ::: "memory"); __builtin_amdgcn_sched_barrier(0); } while (0)

// ---------------- cvt kernels ----------------
__global__ __launch_bounds__(256) void cvt_x_kernel(const float* __restrict__ x,
                                                    __hip_bfloat16* __restrict__ xb) {
    size_t e = (size_t)blockIdx.x * 256 + threadIdx.x;
    const float4* s = reinterpret_cast<const float4*>(x) + e * 2;
    float4 a = s[0], b = s[1];
    Pack8 p;
    p.h2[0] = __float22bfloat162_rn(make_float2(a.x, a.y));
    p.h2[1] = __float22bfloat162_rn(make_float2(a.z, a.w));
    p.h2[2] = __float22bfloat162_rn(make_float2(b.x, b.y));
    p.h2[3] = __float22bfloat162_rn(make_float2(b.z, b.w));
    reinterpret_cast<int4*>(xb)[e] = p.v;
}

__global__ __launch_bounds__(256) void cvt_w_kernel(const float* __restrict__ W,
                                                    __hip_bfloat16* __restrict__ Wb) {
    const size_t total = (size_t)V_DIM * H_DIM / 8;
    size_t stride = (size_t)gridDim.x * 256;
    for (size_t e = (size_t)blockIdx.x * 256 + threadIdx.x; e < total; e += stride) {
        const float4* s = reinterpret_cast<const float4*>(W) + e * 2;
        float4 a = s[0], b = s[1];
        Pack8 p;
        p.h2[0] = __float22bfloat162_rn(make_float2(a.x, a.y));
        p.h2[1] = __float22bfloat162_rn(make_float2(a.z, a.w));
        p.h2[2] = __float22bfloat162_rn(make_float2(b.x, b.y));
        p.h2[3] = __float22bfloat162_rn(make_float2(b.z, b.w));
        reinterpret_cast<int4*>(Wb)[e] = p.v;
    }
}

// ---------------- PIPELINED GEMM: 256x256 tile, counted-vmcnt ring pipeline ----------------
// grid = (N/256, NCH2), block = 512 (8 waves, 2m x 4n, per-wave 128x64 output)
__global__ __launch_bounds__(512, 2) void ce_gemm_pipe(
        const __hip_bfloat16* __restrict__ xb,   // [N][H] bf16
        const __hip_bfloat16* __restrict__ Wb,   // [V][H] bf16
        const int* __restrict__ tgt,
        float2* __restrict__ partials,           // [N][NCH2]
        float* __restrict__ picked) {            // [N]
    __shared__ __align__(16) char ldsbuf[NB * SLOT_BYTES];   // 128 KB ring
    __shared__ float2 mergebuf[256][4];
    __shared__ int ltgt[256];

    const int tid  = threadIdx.x;
    const int lane = tid & 63, wid = tid >> 6;
    const int wm = wid >> 2, wn = wid & 3;
    const int l15 = lane & 15, lg = lane >> 4;
    const int mb = blockIdx.x, vb = blockIdx.y;
    const int rbase = mb * 256, cbase = vb * 256;

    if (tid < 256) ltgt[tid] = tgt[rbase + tid];

    // staging source pointers: granule G = q*512 + tid; r=G>>2, g=G&3;
    // LDS slot (r, g) holds global granule (r, g ^ r ^ (r>>2)) -- involution, matched on read.
    const __hip_bfloat16* srcA[2];
    const __hip_bfloat16* srcB[2];
    #pragma unroll
    for (int q = 0; q < 2; ++q) {
        int G = q * 512 + tid;
        int r = G >> 2, g = G & 3;
        int gs = (g ^ r ^ (r >> 2)) & 3;
        srcA[q] = xb + (size_t)(rbase + r) * H_DIM + gs * 8;
        int vr = cbase + r; if (vr >= V_DIM) vr = V_DIM - 1;     // clamp; masked in epilogue
        srcB[q] = Wb + (size_t)vr * H_DIM + gs * 8;
    }
    // LDS read byte-offsets (swizzled)
    int offA[8], offB[4];
    #pragma unroll
    for (int m = 0; m < 8; ++m) {
        int r = wm * 128 + m * 16 + l15;
        offA[m] = (r * 4 + ((lg ^ r ^ (r >> 2)) & 3)) * 16;
    }
    #pragma unroll
    for (int n = 0; n < 4; ++n) {
        int r = wn * 64 + n * 16 + l15;
        offB[n] = 16384 + (r * 4 + ((lg ^ r ^ (r >> 2)) & 3)) * 16;
    }

    f32x4 acc[8][4] = {};

#define STAGE(KT) do {                                                        \
        char* base_ = ldsbuf + ((KT) & 3) * SLOT_BYTES;                       \
        const int ko_ = (KT) * KS;                                            \
        gload16(srcA[0] + ko_, base_ + (wid * 64) * 16);                      \
        gload16(srcA[1] + ko_, base_ + (512 + wid * 64) * 16);                \
        gload16(srcB[0] + ko_, base_ + 16384 + (wid * 64) * 16);              \
        gload16(srcB[1] + ko_, base_ + 16384 + (512 + wid * 64) * 16);        \
    } while (0)

#define KSTEP(T, VM, DOSTAGE) do {                                            \
        if (DOSTAGE) STAGE((T) + DD);                                         \
        FENCE();                                                              \
        asm volatile("s_waitcnt vmcnt(" #VM ")" ::: "memory");                \
        __builtin_amdgcn_s_barrier();                                         \
        FENCE();                                                              \
        const char* sb_ = ldsbuf + ((T) & 3) * SLOT_BYTES;                    \
        bf16x8 af[8], bfr[4];                                                 \
        _Pragma("unroll") for (int m = 0; m < 8; ++m)                         \
            af[m] = *reinterpret_cast<const bf16x8*>(sb_ + offA[m]);          \
        _Pragma("unroll") for (int n = 0; n < 4; ++n)                         \
            bfr[n] = *reinterpret_cast<const bf16x8*>(sb_ + offB[n]);         \
        __builtin_amdgcn_s_setprio(1);                                        \
        _Pragma("unroll") for (int m = 0; m < 8; ++m)                         \
        _Pragma("unroll") for (int n = 0; n < 4; ++n)                         \
            acc[m][n] = __builtin_amdgcn_mfma_f32_16x16x32_bf16(af[m], bfr[n], acc[m][n], 0, 0, 0); \
        __builtin_amdgcn_s_setprio(0);                                        \
        FENCE();                                                              \
        __builtin_amdgcn_s_barrier();                                         \
        FENCE();                                                              \
    } while (0)

    // prologue: fill 3 slots, no waits
    STAGE(0); STAGE(1); STAGE(2);
    // steady state: 12 outstanding loads allowed (= 3 stages x 4/wave)
    for (int t = 0; t < NT - DD; ++t) KSTEP(t, 12, true);
    KSTEP(NT - 3, 8, false);
    KSTEP(NT - 2, 4, false);
    KSTEP(NT - 1, 0, false);

#undef KSTEP
#undef STAGE

    // ---- fused epilogue: per-row (max, sumexp) over this 256-col chunk + target pick ----
    // C frag layout (verified): col = lane&15, row = (lane>>4)*4 + reg
    #pragma unroll
    for (int m = 0; m < 8; ++m) {
        #pragma unroll
        for (int j = 0; j < 4; ++j) {
            int rl = wm * 128 + m * 16 + lg * 4 + j;
            int tg = ltgt[rl];
            float v4[4];
            float vmax = -INFINITY;
            #pragma unroll
            for (int n = 0; n < 4; ++n) {
                int cg = cbase + wn * 64 + n * 16 + l15;
                float val = acc[m][n][j];
                bool ok = cg < V_DIM;
                v4[n] = ok ? val : -INFINITY;
                if (ok && tg == cg) picked[rbase + rl] = val;
                vmax = fmaxf(vmax, v4[n]);
            }
            #pragma unroll
            for (int msk = 1; msk <= 8; msk <<= 1)
                vmax = fmaxf(vmax, __shfl_xor(vmax, msk));
            float ssum = 0.f;
            #pragma unroll
            for (int n = 0; n < 4; ++n)
                ssum += (v4[n] == -INFINITY) ? 0.f : __expf(v4[n] - vmax);
            #pragma unroll
            for (int msk = 1; msk <= 8; msk <<= 1)
                ssum += __shfl_xor(ssum, msk);
            if (l15 == 0) mergebuf[rl][wn] = make_float2(vmax, ssum);
        }
    }
    __syncthreads();
    if (tid < 256) {
        float M = -INFINITY, sm = 0.f;
        #pragma unroll
        for (int c = 0; c < 4; ++c) {
            float2 p = mergebuf[tid][c];
            if (p.x > -INFINITY) {
                float M2 = fmaxf(M, p.x);
                sm = sm * __expf(M - M2) + p.y * __expf(p.x - M2);
                M = M2;
            }
        }
        partials[(size_t)(rbase + tid) * NCH2 + vb] = make_float2(M, sm);
    }
}

// ---------------- FALLBACK GEMM (fp32 W, in-register cvt, 128^2) ----------------
__global__ __launch_bounds__(256) void ce_gemm_kernel(
        const __hip_bfloat16* __restrict__ xb, const float* __restrict__ W,
        const int* __restrict__ tgt, float2* __restrict__ partials, float* __restrict__ picked) {
    __shared__ __hip_bfloat16 lA[BM * LDT];
    __shared__ __hip_bfloat16 lB[BN * LDT];
    __shared__ float2 mergebuf[BM][2];
    __shared__ int ltgt[BM];
    const int tid = threadIdx.x, mb = blockIdx.x, vb = blockIdx.y;
    const int rbase = mb * BM, cbase = vb * BN;
    const int lane = tid & 63, wid = tid >> 6;
    const int wr = wid >> 1, wc = wid & 1, l15 = lane & 15, lg = lane >> 4;
    if (tid < BM) ltgt[tid] = tgt[rbase + tid];
    f32x4 acc[4][4] = {};
    for (int s = 0; s < H_DIM / BK; ++s) {
        const int k0 = s * BK;
        __syncthreads();
        #pragma unroll
        for (int it = 0; it < 4; ++it) {
            int e = it * 256 + tid, r = e >> 3, c8 = e & 7;
            int4 v = *reinterpret_cast<const int4*>(xb + (size_t)(rbase + r) * H_DIM + k0 + c8 * 8);
            *reinterpret_cast<int4*>(&lA[r * LDT + c8 * 8]) = v;
        }
        #pragma unroll
        for (int it = 0; it < 4; ++it) {
            int e = it * 256 + tid, r = e >> 3, c8 = e & 7;
            int v = cbase + r; if (v >= V_DIM) v = V_DIM - 1;
            const float4* src = reinterpret_cast<const float4*>(W + (size_t)v * H_DIM + k0 + c8 * 8);
            float4 f0 = src[0], f1 = src[1];
            Pack8 p;
            p.h2[0] = __float22bfloat162_rn(make_float2(f0.x, f0.y));
            p.h2[1] = __float22bfloat162_rn(make_float2(f0.z, f0.w));
            p.h2[2] = __float22bfloat162_rn(make_float2(f1.x, f1.y));
            p.h2[3] = __float22bfloat162_rn(make_float2(f1.z, f1.w));
            *reinterpret_cast<int4*>(&lB[r * LDT + c8 * 8]) = p.v;
        }
        __syncthreads();
        #pragma unroll
        for (int kk = 0; kk < 2; ++kk) {
            bf16x8 af[4], bfr[4];
            #pragma unroll
            for (int m = 0; m < 4; ++m)
                af[m] = *reinterpret_cast<const bf16x8*>(&lA[(wr * 64 + m * 16 + l15) * LDT + kk * 32 + lg * 8]);
            #pragma unroll
            for (int n = 0; n < 4; ++n)
                bfr[n] = *reinterpret_cast<const bf16x8*>(&lB[(wc * 64 + n * 16 + l15) * LDT + kk * 32 + lg * 8]);
            #pragma unroll
            for (int m = 0; m < 4; ++m)
                #pragma unroll
                for (int n = 0; n < 4; ++n)
                    acc[m][n] = __builtin_amdgcn_mfma_f32_16x16x32_bf16(af[m], bfr[n], acc[m][n], 0, 0, 0);
        }
    }
    #pragma unroll
    for (int m = 0; m < 4; ++m) {
        #pragma unroll
        for (int j = 0; j < 4; ++j) {
            int rl = wr * 64 + m * 16 + lg * 4 + j;
            int tg = ltgt[rl];
            float v4[4]; float vmax = -INFINITY;
            #pragma unroll
            for (int n = 0; n < 4; ++n) {
                int cg = cbase + wc * 64 + n * 16 + l15;
                float val = acc[m][n][j];
                bool ok = cg < V_DIM;
                v4[n] = ok ? val : -INFINITY;
                if (ok && tg == cg) picked[rbase + rl] = val;
                vmax = fmaxf(vmax, v4[n]);
            }
            #pragma unroll
            for (int msk = 1; msk <= 8; msk <<= 1) vmax = fmaxf(vmax, __shfl_xor(vmax, msk));
            float ssum = 0.f;
            #pragma unroll
            for (int n = 0; n < 4; ++n) ssum += (v4[n] == -INFINITY) ? 0.f : __expf(v4[n] - vmax);
            #pragma unroll
            for (int msk = 1; msk <= 8; msk <<= 1) ssum += __shfl_xor(ssum, msk);
            if (l15 == 0) mergebuf[rl][wc] = make_float2(vmax, ssum);
        }
    }
    __syncthreads();
    if (tid < BM) {
        float2 p0 = mergebuf[tid][0], p1 = mergebuf[tid][1];
        float M = fmaxf(p0.x, p1.x);
        float sm = 0.f;
        if (p0.x > -INFINITY) sm += p0.y * __expf(p0.x - M);
        if (p1.x > -INFINITY) sm += p1.y * __expf(p1.x - M);
        partials[(size_t)(rbase + tid) * NCHUNK_FB + vb] = make_float2(M, sm);
    }
}

// ---------------- combine + final ----------------
__global__ __launch_bounds__(256) void ce_combine_kernel(
        const float2* __restrict__ partials, const float* __restrict__ picked,
        const int* __restrict__ tgt, float2* __restrict__ blockSums, int nchunk) {
    __shared__ float2 wsum[4];
    int tid = threadIdx.x, lane = tid & 63, wave = tid >> 6;
    int w = blockIdx.x * 4 + wave;
    float sum = 0.f, cnt = 0.f;
    for (int row = w; row < N_TOK; row += 256) {
        float m = -INFINITY, sacc = 0.f;
        for (int c = lane; c < nchunk; c += 64) {
            float2 p = partials[(size_t)row * nchunk + c];
            float M = fmaxf(m, p.x);
            sacc = sacc * __expf(m - M) + p.y * __expf(p.x - M);
            m = M;
        }
        #pragma unroll
        for (int msk = 1; msk < 64; msk <<= 1) {
            float om = __shfl_xor(m, msk), os = __shfl_xor(sacc, msk);
            float M = fmaxf(m, om);
            sacc = sacc * __expf(m - M) + os * __expf(om - M);
            m = M;
        }
        if (lane == 0) {
            int t = tgt[row];
            if (t != IGNORE_IDX) { sum += (m + __logf(sacc)) - picked[row]; cnt += 1.f; }
        }
    }
    if (lane == 0) wsum[wave] = make_float2(sum, cnt);
    __syncthreads();
    if (tid == 0) {
        float S = 0.f, C = 0.f;
        #pragma unroll
        for (int i = 0; i < 4; ++i) { S += wsum[i].x; C += wsum[i].y; }
        blockSums[blockIdx.x] = make_float2(S, C);
    }
}

__global__ void ce_final_kernel(const float2* __restrict__ blockSums, float* __restrict__ out) {
    int lane = threadIdx.x;
    float2 p = blockSums[lane];
    float S = p.x, C = p.y;
    #pragma unroll
    for (int msk = 1; msk < 64; msk <<= 1) { S += __shfl_xor(S, msk); C += __shfl_xor(C, msk); }
    if (lane == 0) out[0] = S / fmaxf(C, 1.f);
}

extern "C" void kernel_launch(void* const* d_in, const int* in_sizes, int n_in,
                              void* d_out, int out_size, void* d_ws, size_t ws_size,
                              hipStream_t stream) {
    const float* x   = (const float*)d_in[0];
    const int*   tgt = (const int*)d_in[1];
    const float* W   = (const float*)d_in[2];
    float* out = (float*)d_out;
    char* ws = (char*)d_ws;

    if (ws_size >= ((size_t)142 << 20)) {
        // fast path: xb@0 (8.4MB), Wb@16MB (103MB), partials@120MB (6.5MB),
        // picked@140MB (16KB), blockSums@141MB
        __hip_bfloat16* xb = (__hip_bfloat16*)ws;
        __hip_bfloat16* Wb = (__hip_bfloat16*)(ws + ((size_t)16 << 20));
        float2* partials   = (float2*)(ws + ((size_t)120 << 20));
        float*  picked     = (float*)(ws + ((size_t)140 << 20));
        float2* blockSums  = (float2*)(ws + ((size_t)141 << 20));

        cvt_x_kernel<<<(N_TOK * H_DIM) / (256 * 8), 256, 0, stream>>>(x, xb);
        cvt_w_kernel<<<2048, 256, 0, stream>>>(W, Wb);
        dim3 grid(N_TOK / 256, NCH2);
        ce_gemm_pipe<<<grid, 512, 0, stream>>>(xb, Wb, tgt, partials, picked);
        ce_combine_kernel<<<64, 256, 0, stream>>>(partials, picked, tgt, blockSums, NCH2);
        ce_final_kernel<<<1, 64, 0, stream>>>(blockSums, out);
    } else {
        // fallback (round-1 layout)
        __hip_bfloat16* xb = (__hip_bfloat16*)ws;
        float2* partials   = (float2*)(ws + (8u << 20));
        float*  picked     = (float*)(ws + (21u << 20));
        float2* blockSums  = (float2*)(ws + (21u << 20) + (64u << 10));

        cvt_x_kernel<<<(N_TOK * H_DIM) / (256 * 8), 256, 0, stream>>>(x, xb);
        dim3 grid(N_TOK / BM, NCHUNK_FB);
        ce_gemm_kernel<<<grid, 256, 0, stream>>>(xb, W, tgt, partials, picked);
        ce_combine_kernel<<<64, 256, 0, stream>>>(partials, picked, tgt, blockSums, NCHUNK_FB);
        ce_final_kernel<<<1, 64, 0, stream>>>(blockSums, out);
    }
}

// Round 4
// 595.996 us; speedup vs baseline: 1.2545x; 1.2545x over previous
//
#include <hip/hip_runtime.h>
#include <hip/hip_bf16.h>

#define N_TOK 4096
#define H_DIM 1024
#define V_DIM 50257
#define IGNORE_IDX (-100)

// fallback-path params
#define BM 128
#define BN 128
#define BK_FB 64
#define NCHUNK_FB ((V_DIM + BN - 1) / BN)   /* 393 */
#define LDT 72

// 8-phase path params
#define NKT 16                    /* K-tiles of 64: H=1024 */
#define NCH2 ((V_DIM + 255) / 256) /* 197 */

typedef __attribute__((ext_vector_type(8))) short bf16x8;
typedef __attribute__((ext_vector_type(4))) float f32x4;

union Pack8 { __hip_bfloat162 h2[4]; int4 v; };

__device__ __forceinline__ void gload16(const void* g, void* l) {
    __builtin_amdgcn_global_load_lds(
        (const __attribute__((address_space(1))) unsigned int*)g,
        (__attribute__((address_space(3))) unsigned int*)l,
        16, 0, 0);
}

#define FENCE() do { asm volatile("" ::: "memory"); __builtin_amdgcn_sched_barrier(0); } while (0)

// ---------------- cvt kernels ----------------
__global__ __launch_bounds__(256) void cvt_x_kernel(const float* __restrict__ x,
                                                    __hip_bfloat16* __restrict__ xb) {
    size_t e = (size_t)blockIdx.x * 256 + threadIdx.x;
    const float4* s = reinterpret_cast<const float4*>(x) + e * 2;
    float4 a = s[0], b = s[1];
    Pack8 p;
    p.h2[0] = __float22bfloat162_rn(make_float2(a.x, a.y));
    p.h2[1] = __float22bfloat162_rn(make_float2(a.z, a.w));
    p.h2[2] = __float22bfloat162_rn(make_float2(b.x, b.y));
    p.h2[3] = __float22bfloat162_rn(make_float2(b.z, b.w));
    reinterpret_cast<int4*>(xb)[e] = p.v;
}

__global__ __launch_bounds__(256) void cvt_w_kernel(const float* __restrict__ W,
                                                    __hip_bfloat16* __restrict__ Wb) {
    const size_t total = (size_t)V_DIM * H_DIM / 8;
    size_t stride = (size_t)gridDim.x * 256;
    for (size_t e = (size_t)blockIdx.x * 256 + threadIdx.x; e < total; e += stride) {
        const float4* s = reinterpret_cast<const float4*>(W) + e * 2;
        float4 a = s[0], b = s[1];
        Pack8 p;
        p.h2[0] = __float22bfloat162_rn(make_float2(a.x, a.y));
        p.h2[1] = __float22bfloat162_rn(make_float2(a.z, a.w));
        p.h2[2] = __float22bfloat162_rn(make_float2(b.x, b.y));
        p.h2[3] = __float22bfloat162_rn(make_float2(b.z, b.w));
        reinterpret_cast<int4*>(Wb)[e] = p.v;
    }
}

// ---------------- 8-PHASE GEMM: 256x256 tile, BK=64, dbuf, counted vmcnt ----------------
// grid = (N/256, NCH2), block = 512 (8 waves, 2m x 4n, per-wave 128x64 output)
// LDS regions per buffer (64KB): A0@0 A1@16K B0@32K B1@48K; 2 buffers = 128KB.
// Swizzle (proven 0-conflict in R2): 16B granule g of row r stored at slot g^(r&7);
// row stride 128B. Applied source-side for global_load_lds + read-side for ds_read.
__global__ __launch_bounds__(512, 2) void ce_gemm_8ph(
        const __hip_bfloat16* __restrict__ xb,   // [N][H] bf16
        const __hip_bfloat16* __restrict__ Wb,   // [V][H] bf16
        const int* __restrict__ tgt,
        float2* __restrict__ partials,           // [N][NCH2]
        float* __restrict__ picked) {            // [N]
    __shared__ __align__(16) char ldsbuf[131072];
    __shared__ float2 mergebuf[256][4];
    __shared__ int ltgt[256];

    const int tid  = threadIdx.x;
    const int lane = tid & 63, wid = tid >> 6;
    const int wm = wid >> 2, wn = wid & 3;
    const int l15 = lane & 15, lg = lane >> 4;
    const int mb = blockIdx.x, vb = blockIdx.y;
    const int rbase = mb * 256, cbase = vb * 256;

    if (tid < 256) ltgt[tid] = tgt[rbase + tid];

    // staging source pointers [q][half]; granule G=q*512+tid, r=G>>3, g=G&7,
    // source granule = g^(r&7)  (inverse-swizzle on source, linear LDS dest)
    const __hip_bfloat16* sA[2][2];
    const __hip_bfloat16* sB[2][2];
    #pragma unroll
    for (int q = 0; q < 2; ++q) {
        int G = q * 512 + tid;
        int r = G >> 3, g = G & 7;
        int gs = g ^ (r & 7);
        #pragma unroll
        for (int h = 0; h < 2; ++h) {
            sA[q][h] = xb + (size_t)(rbase + h * 128 + r) * H_DIM + gs * 8;
            int vr = cbase + h * 128 + r; if (vr >= V_DIM) vr = V_DIM - 1;  // clamp; masked in epilogue
            sB[q][h] = Wb + (size_t)vr * H_DIM + gs * 8;
        }
    }
    // LDS read byte-offsets (kk=0; kk=1 is ^64 since g=kk*4+lg toggles slot bit2)
    int aoff[2][4], boff[4];
    #pragma unroll
    for (int mh = 0; mh < 2; ++mh)
        #pragma unroll
        for (int m = 0; m < 4; ++m) {
            int r = wm * 128 + mh * 64 + m * 16 + l15;
            aoff[mh][m] = r * 128 + ((lg ^ (r & 7)) << 4);
        }
    #pragma unroll
    for (int n = 0; n < 4; ++n) {
        int r = wn * 64 + n * 16 + l15;
        boff[n] = 32768 + r * 128 + ((lg ^ (r & 7)) << 4);
    }

    f32x4 acc[8][4] = {};
    bf16x8 af[4][2], bf[4][2];

    // region HH: 0=A0 1=A1 2=B0 3=B1
#define STG(KT, HH) do {                                                      \
        char* db_ = ldsbuf + (((KT) & 1) << 16) + ((HH) << 14) + wid * 1024;  \
        const int ko_ = (KT) * 64;                                            \
        if ((HH) < 2) {                                                       \
            gload16(sA[0][(HH)] + ko_, db_);                                  \
            gload16(sA[1][(HH)] + ko_, db_ + 8192);                           \
        } else {                                                              \
            gload16(sB[0][(HH) - 2] + ko_, db_);                              \
            gload16(sB[1][(HH) - 2] + ko_, db_ + 8192);                       \
        }                                                                     \
    } while (0)

    // prologue: kt0 all 4 halves, then kt1's B halves (6 half-tiles, 12 loads)
    STG(0, 0); STG(0, 1); STG(0, 2); STG(0, 3);
    STG(1, 2); STG(1, 3);

    for (int kt = 0; kt < NKT; ++kt) {
        // ---- K-tile switch: publish buffer (kt). Newest 4 loads = kt+1's B halves.
        FENCE();
        if (kt == NKT - 1) asm volatile("s_waitcnt vmcnt(0)" ::: "memory");
        else               asm volatile("s_waitcnt vmcnt(4)" ::: "memory");
        __builtin_amdgcn_s_barrier();
        FENCE();
        const char* bb = ldsbuf + ((kt & 1) << 16);

        // ---- q0: read A-half0 (8) + B n=0,1 (4); stage (kt+1, A0); MFMA m0-3 x n0-1
        #pragma unroll
        for (int m = 0; m < 4; ++m) {
            af[m][0] = *reinterpret_cast<const bf16x8*>(bb + aoff[0][m]);
            af[m][1] = *reinterpret_cast<const bf16x8*>(bb + (aoff[0][m] ^ 64));
        }
        #pragma unroll
        for (int n = 0; n < 2; ++n) {
            bf[n][0] = *reinterpret_cast<const bf16x8*>(bb + boff[n]);
            bf[n][1] = *reinterpret_cast<const bf16x8*>(bb + (boff[n] ^ 64));
        }
        if (kt + 1 < NKT) STG(kt + 1, 0);
        __builtin_amdgcn_s_setprio(1);
        #pragma unroll
        for (int m = 0; m < 4; ++m)
            #pragma unroll
            for (int n = 0; n < 2; ++n)
                #pragma unroll
                for (int kk = 0; kk < 2; ++kk)
                    acc[m][n] = __builtin_amdgcn_mfma_f32_16x16x32_bf16(af[m][kk], bf[n][kk], acc[m][n], 0, 0, 0);
        __builtin_amdgcn_s_setprio(0);
        FENCE(); __builtin_amdgcn_s_barrier(); FENCE();

        // ---- q1: read B n=2,3 (4); stage (kt+1, A1); MFMA m0-3 x n2-3
        #pragma unroll
        for (int n = 2; n < 4; ++n) {
            bf[n][0] = *reinterpret_cast<const bf16x8*>(bb + boff[n]);
            bf[n][1] = *reinterpret_cast<const bf16x8*>(bb + (boff[n] ^ 64));
        }
        if (kt + 1 < NKT) STG(kt + 1, 1);
        __builtin_amdgcn_s_setprio(1);
        #pragma unroll
        for (int m = 0; m < 4; ++m)
            #pragma unroll
            for (int n = 2; n < 4; ++n)
                #pragma unroll
                for (int kk = 0; kk < 2; ++kk)
                    acc[m][n] = __builtin_amdgcn_mfma_f32_16x16x32_bf16(af[m][kk], bf[n][kk], acc[m][n], 0, 0, 0);
        __builtin_amdgcn_s_setprio(0);
        FENCE(); __builtin_amdgcn_s_barrier(); FENCE();

        // ---- q2: read A-half1 (8, overwrite af); stage (kt+2, B0); MFMA m4-7 x n0-1
        #pragma unroll
        for (int m = 0; m < 4; ++m) {
            af[m][0] = *reinterpret_cast<const bf16x8*>(bb + aoff[1][m]);
            af[m][1] = *reinterpret_cast<const bf16x8*>(bb + (aoff[1][m] ^ 64));
        }
        if (kt + 2 < NKT) STG(kt + 2, 2);
        __builtin_amdgcn_s_setprio(1);
        #pragma unroll
        for (int m = 0; m < 4; ++m)
            #pragma unroll
            for (int n = 0; n < 2; ++n)
                #pragma unroll
                for (int kk = 0; kk < 2; ++kk)
                    acc[4 + m][n] = __builtin_amdgcn_mfma_f32_16x16x32_bf16(af[m][kk], bf[n][kk], acc[4 + m][n], 0, 0, 0);
        __builtin_amdgcn_s_setprio(0);
        FENCE(); __builtin_amdgcn_s_barrier(); FENCE();

        // ---- q3: stage (kt+2, B1); MFMA m4-7 x n2-3  (switch barrier follows)
        if (kt + 2 < NKT) STG(kt + 2, 3);
        __builtin_amdgcn_s_setprio(1);
        #pragma unroll
        for (int m = 0; m < 4; ++m)
            #pragma unroll
            for (int n = 2; n < 4; ++n)
                #pragma unroll
                for (int kk = 0; kk < 2; ++kk)
                    acc[4 + m][n] = __builtin_amdgcn_mfma_f32_16x16x32_bf16(af[m][kk], bf[n][kk], acc[4 + m][n], 0, 0, 0);
        __builtin_amdgcn_s_setprio(0);
    }
#undef STG

    // ---- fused epilogue: per-row (max, sumexp) over this 256-col chunk + target pick ----
    // C frag layout: col = lane&15, row = (lane>>4)*4 + reg
    #pragma unroll
    for (int m = 0; m < 8; ++m) {
        #pragma unroll
        for (int j = 0; j < 4; ++j) {
            int rl = wm * 128 + m * 16 + lg * 4 + j;
            int tg = ltgt[rl];
            float v4[4];
            float vmax = -INFINITY;
            #pragma unroll
            for (int n = 0; n < 4; ++n) {
                int cg = cbase + wn * 64 + n * 16 + l15;
                float val = acc[m][n][j];
                bool ok = cg < V_DIM;
                v4[n] = ok ? val : -INFINITY;
                if (ok && tg == cg) picked[rbase + rl] = val;
                vmax = fmaxf(vmax, v4[n]);
            }
            #pragma unroll
            for (int msk = 1; msk <= 8; msk <<= 1)
                vmax = fmaxf(vmax, __shfl_xor(vmax, msk));
            float ssum = 0.f;
            #pragma unroll
            for (int n = 0; n < 4; ++n)
                ssum += (v4[n] == -INFINITY) ? 0.f : __expf(v4[n] - vmax);
            #pragma unroll
            for (int msk = 1; msk <= 8; msk <<= 1)
                ssum += __shfl_xor(ssum, msk);
            if (l15 == 0) mergebuf[rl][wn] = make_float2(vmax, ssum);
        }
    }
    __syncthreads();
    if (tid < 256) {
        float M = -INFINITY, sm = 0.f;
        #pragma unroll
        for (int c = 0; c < 4; ++c) {
            float2 p = mergebuf[tid][c];
            if (p.x > -INFINITY) {
                float M2 = fmaxf(M, p.x);
                sm = sm * __expf(M - M2) + p.y * __expf(p.x - M2);
                M = M2;
            }
        }
        partials[(size_t)(rbase + tid) * NCH2 + vb] = make_float2(M, sm);
    }
}

// ---------------- FALLBACK GEMM (fp32 W, in-register cvt, 128^2) ----------------
__global__ __launch_bounds__(256) void ce_gemm_kernel(
        const __hip_bfloat16* __restrict__ xb, const float* __restrict__ W,
        const int* __restrict__ tgt, float2* __restrict__ partials, float* __restrict__ picked) {
    __shared__ __hip_bfloat16 lA[BM * LDT];
    __shared__ __hip_bfloat16 lB[BN * LDT];
    __shared__ float2 mergebuf[BM][2];
    __shared__ int ltgt[BM];
    const int tid = threadIdx.x, mb = blockIdx.x, vb = blockIdx.y;
    const int rbase = mb * BM, cbase = vb * BN;
    const int lane = tid & 63, wid = tid >> 6;
    const int wr = wid >> 1, wc = wid & 1, l15 = lane & 15, lg = lane >> 4;
    if (tid < BM) ltgt[tid] = tgt[rbase + tid];
    f32x4 acc[4][4] = {};
    for (int s = 0; s < H_DIM / BK_FB; ++s) {
        const int k0 = s * BK_FB;
        __syncthreads();
        #pragma unroll
        for (int it = 0; it < 4; ++it) {
            int e = it * 256 + tid, r = e >> 3, c8 = e & 7;
            int4 v = *reinterpret_cast<const int4*>(xb + (size_t)(rbase + r) * H_DIM + k0 + c8 * 8);
            *reinterpret_cast<int4*>(&lA[r * LDT + c8 * 8]) = v;
        }
        #pragma unroll
        for (int it = 0; it < 4; ++it) {
            int e = it * 256 + tid, r = e >> 3, c8 = e & 7;
            int v = cbase + r; if (v >= V_DIM) v = V_DIM - 1;
            const float4* src = reinterpret_cast<const float4*>(W + (size_t)v * H_DIM + k0 + c8 * 8);
            float4 f0 = src[0], f1 = src[1];
            Pack8 p;
            p.h2[0] = __float22bfloat162_rn(make_float2(f0.x, f0.y));
            p.h2[1] = __float22bfloat162_rn(make_float2(f0.z, f0.w));
            p.h2[2] = __float22bfloat162_rn(make_float2(f1.x, f1.y));
            p.h2[3] = __float22bfloat162_rn(make_float2(f1.z, f1.w));
            *reinterpret_cast<int4*>(&lB[r * LDT + c8 * 8]) = p.v;
        }
        __syncthreads();
        #pragma unroll
        for (int kk = 0; kk < 2; ++kk) {
            bf16x8 af[4], bfr[4];
            #pragma unroll
            for (int m = 0; m < 4; ++m)
                af[m] = *reinterpret_cast<const bf16x8*>(&lA[(wr * 64 + m * 16 + l15) * LDT + kk * 32 + lg * 8]);
            #pragma unroll
            for (int n = 0; n < 4; ++n)
                bfr[n] = *reinterpret_cast<const bf16x8*>(&lB[(wc * 64 + n * 16 + l15) * LDT + kk * 32 + lg * 8]);
            #pragma unroll
            for (int m = 0; m < 4; ++m)
                #pragma unroll
                for (int n = 0; n < 4; ++n)
                    acc[m][n] = __builtin_amdgcn_mfma_f32_16x16x32_bf16(af[m], bfr[n], acc[m][n], 0, 0, 0);
        }
    }
    #pragma unroll
    for (int m = 0; m < 4; ++m) {
        #pragma unroll
        for (int j = 0; j < 4; ++j) {
            int rl = wr * 64 + m * 16 + lg * 4 + j;
            int tg = ltgt[rl];
            float v4[4]; float vmax = -INFINITY;
            #pragma unroll
            for (int n = 0; n < 4; ++n) {
                int cg = cbase + wc * 64 + n * 16 + l15;
                float val = acc[m][n][j];
                bool ok = cg < V_DIM;
                v4[n] = ok ? val : -INFINITY;
                if (ok && tg == cg) picked[rbase + rl] = val;
                vmax = fmaxf(vmax, v4[n]);
            }
            #pragma unroll
            for (int msk = 1; msk <= 8; msk <<= 1) vmax = fmaxf(vmax, __shfl_xor(vmax, msk));
            float ssum = 0.f;
            #pragma unroll
            for (int n = 0; n < 4; ++n) ssum += (v4[n] == -INFINITY) ? 0.f : __expf(v4[n] - vmax);
            #pragma unroll
            for (int msk = 1; msk <= 8; msk <<= 1) ssum += __shfl_xor(ssum, msk);
            if (l15 == 0) mergebuf[rl][wc] = make_float2(vmax, ssum);
        }
    }
    __syncthreads();
    if (tid < BM) {
        float2 p0 = mergebuf[tid][0], p1 = mergebuf[tid][1];
        float M = fmaxf(p0.x, p1.x);
        float sm = 0.f;
        if (p0.x > -INFINITY) sm += p0.y * __expf(p0.x - M);
        if (p1.x > -INFINITY) sm += p1.y * __expf(p1.x - M);
        partials[(size_t)(rbase + tid) * NCHUNK_FB + vb] = make_float2(M, sm);
    }
}

// ---------------- combine + final ----------------
__global__ __launch_bounds__(256) void ce_combine_kernel(
        const float2* __restrict__ partials, const float* __restrict__ picked,
        const int* __restrict__ tgt, float2* __restrict__ blockSums, int nchunk) {
    __shared__ float2 wsum[4];
    int tid = threadIdx.x, lane = tid & 63, wave = tid >> 6;
    int w = blockIdx.x * 4 + wave;
    float sum = 0.f, cnt = 0.f;
    for (int row = w; row < N_TOK; row += 256) {
        float m = -INFINITY, sacc = 0.f;
        for (int c = lane; c < nchunk; c += 64) {
            float2 p = partials[(size_t)row * nchunk + c];
            float M = fmaxf(m, p.x);
            sacc = sacc * __expf(m - M) + p.y * __expf(p.x - M);
            m = M;
        }
        #pragma unroll
        for (int msk = 1; msk < 64; msk <<= 1) {
            float om = __shfl_xor(m, msk), os = __shfl_xor(sacc, msk);
            float M = fmaxf(m, om);
            sacc = sacc * __expf(m - M) + os * __expf(om - M);
            m = M;
        }
        if (lane == 0) {
            int t = tgt[row];
            if (t != IGNORE_IDX) { sum += (m + __logf(sacc)) - picked[row]; cnt += 1.f; }
        }
    }
    if (lane == 0) wsum[wave] = make_float2(sum, cnt);
    __syncthreads();
    if (tid == 0) {
        float S = 0.f, C = 0.f;
        #pragma unroll
        for (int i = 0; i < 4; ++i) { S += wsum[i].x; C += wsum[i].y; }
        blockSums[blockIdx.x] = make_float2(S, C);
    }
}

__global__ void ce_final_kernel(const float2* __restrict__ blockSums, float* __restrict__ out) {
    int lane = threadIdx.x;
    float2 p = blockSums[lane];
    float S = p.x, C = p.y;
    #pragma unroll
    for (int msk = 1; msk < 64; msk <<= 1) { S += __shfl_xor(S, msk); C += __shfl_xor(C, msk); }
    if (lane == 0) out[0] = S / fmaxf(C, 1.f);
}

extern "C" void kernel_launch(void* const* d_in, const int* in_sizes, int n_in,
                              void* d_out, int out_size, void* d_ws, size_t ws_size,
                              hipStream_t stream) {
    const float* x   = (const float*)d_in[0];
    const int*   tgt = (const int*)d_in[1];
    const float* W   = (const float*)d_in[2];
    float* out = (float*)d_out;
    char* ws = (char*)d_ws;

    if (ws_size >= ((size_t)142 << 20)) {
        // fast path: xb@0 (8.4MB), Wb@16MB (103MB), partials@120MB (6.5MB),
        // picked@140MB (16KB), blockSums@141MB
        __hip_bfloat16* xb = (__hip_bfloat16*)ws;
        __hip_bfloat16* Wb = (__hip_bfloat16*)(ws + ((size_t)16 << 20));
        float2* partials   = (float2*)(ws + ((size_t)120 << 20));
        float*  picked     = (float*)(ws + ((size_t)140 << 20));
        float2* blockSums  = (float2*)(ws + ((size_t)141 << 20));

        cvt_x_kernel<<<(N_TOK * H_DIM) / (256 * 8), 256, 0, stream>>>(x, xb);
        cvt_w_kernel<<<2048, 256, 0, stream>>>(W, Wb);
        dim3 grid(N_TOK / 256, NCH2);
        ce_gemm_8ph<<<grid, 512, 0, stream>>>(xb, Wb, tgt, partials, picked);
        ce_combine_kernel<<<64, 256, 0, stream>>>(partials, picked, tgt, blockSums, NCH2);
        ce_final_kernel<<<1, 64, 0, stream>>>(blockSums, out);
    } else {
        // fallback (round-1 layout)
        __hip_bfloat16* xb = (__hip_bfloat16*)ws;
        float2* partials   = (float2*)(ws + (8u << 20));
        float*  picked     = (float*)(ws + (21u << 20));
        float2* blockSums  = (float2*)(ws + (21u << 20) + (64u << 10));

        cvt_x_kernel<<<(N_TOK * H_DIM) / (256 * 8), 256, 0, stream>>>(x, xb);
        dim3 grid(N_TOK / BM, NCHUNK_FB);
        ce_gemm_kernel<<<grid, 256, 0, stream>>>(xb, W, tgt, partials, picked);
        ce_combine_kernel<<<64, 256, 0, stream>>>(partials, picked, tgt, blockSums, NCHUNK_FB);
        ce_final_kernel<<<1, 64, 0, stream>>>(blockSums, out);
    }
}